// Round 8
// baseline (144.519 us; speedup 1.0000x reference)
//
#include <hip/hip_runtime.h>
#include <hip/hip_bf16.h>

// B=2048, T=128, I=130, H=10, 3H=30, D1=20
// Phase 1 (xi_gemm): xi = x @ Wih^T + bih, MFMA bf16 hi/lo 3-term emulation.
//   Round-8 change: ONE 16-row tile per wave, 32768 independent waves.
//   Round 7 (4 serial tiles/wave) measured VALU 14% / MFMA 4.5% / HBM 16% /
//   occ 19% -> pure latency bound from the per-wave vmcnt(0)+LDS chain.
//   Now: issue the tile's 9 coalesced float4 wave-loads FIRST, do B-frag
//   setup under the load latency, single LDS stage, compute, store, exit.
//   No inter-tile chains; TLP (16 waves/CU, LDS-capped) hides HBM latency.
// Phase 2 (gru_scan): h-state broadcast via __shfl (loop-invariant lane
//   addresses) instead of LDS write->read roundtrip (~120 cyc/step serial).
// Fallback: monolithic kernel if ws_size < 63 MB.

#define BB 2048
#define TT 128
#define II 130
#define ROWS_PER_GRU (BB * TT)          // 262144
#define ROWS_TOTAL   (2 * ROWS_PER_GRU) // 524288

typedef __attribute__((ext_vector_type(8))) short short8v;  // 8 bf16
typedef __attribute__((ext_vector_type(4))) float f32x4;

__device__ __forceinline__ float sigmoidf_fast(float x) {
    return __fdividef(1.f, 1.f + __expf(-x));
}
__device__ __forceinline__ float tanhf_fast(float x) {
    float ax = fabsf(x);
    float e = __expf(-2.f * ax);
    float t = __fdividef(1.f - e, 1.f + e);
    return copysignf(t, x);
}

// truncation split of 2 fp32 -> packed bf16-hi pair + bf16-lo pair
__device__ __forceinline__ void split2(float x0, float x1,
                                       unsigned& hi, unsigned& lo) {
    unsigned u0 = __float_as_uint(x0), u1 = __float_as_uint(x1);
    hi = (u0 >> 16) | (u1 & 0xffff0000u);
    float f0 = __uint_as_float(u0 & 0xffff0000u);
    float f1 = __uint_as_float(u1 & 0xffff0000u);
    unsigned l0 = __float_as_uint(x0 - f0);
    unsigned l1 = __float_as_uint(x1 - f1);
    lo = (l0 >> 16) | (l1 & 0xffff0000u);
}

union U8 { unsigned u[4]; short8v v; };

// split 8 consecutive fp32 (8B-aligned, any addrspace) into bf16x8 hi/lo
__device__ __forceinline__ void load_split(const float* __restrict__ p,
                                           short8v& hi, short8v& lo) {
    U8 H, L;
    #pragma unroll
    for (int i = 0; i < 4; ++i) {
        const float2 xy = *(const float2*)(p + 2 * i);
        split2(xy.x, xy.y, H.u[i], L.u[i]);
    }
    hi = H.v; lo = L.v;
}

// ---------------- Phase 1: input projection via MFMA ----------------
__global__ __launch_bounds__(256)
void xi_gemm(const float* __restrict__ ru, const float* __restrict__ en,
             const float* __restrict__ ruWih, const float* __restrict__ rubih,
             const float* __restrict__ enWih, const float* __restrict__ enbih,
             float* __restrict__ xi)
{
    const int tid  = threadIdx.x;
    const int wv   = tid >> 6;
    const int lane = tid & 63;
    const int lr   = lane & 15;          // A-row / B-col / C-col slot
    const int lk   = lane >> 4;          // k-subblock (0..3)
    const int w    = blockIdx.x * 4 + wv;            // wave 0..32767
    const int gru  = (w >= 16384);
    const long row0 = (long)(w & 16383) * 16;        // local row in this gru

    const float* __restrict__ X   = gru ? en    : ru;
    const float* __restrict__ Wf  = gru ? enWih : ruWih;
    const float* __restrict__ bih = gru ? enbih : rubih;

    // ---- 1) issue the A-tile loads IMMEDIATELY (16 rows = 520 float4) ----
    const float4* __restrict__ src = (const float4*)X + row0 * II / 4;
    const float4 pf0 = src[lane];
    const float4 pf1 = src[64 + lane];
    const float4 pf2 = src[128 + lane];
    const float4 pf3 = src[192 + lane];
    const float4 pf4 = src[256 + lane];
    const float4 pf5 = src[320 + lane];
    const float4 pf6 = src[384 + lane];
    const float4 pf7 = src[448 + lane];
    const float4 pft = (lane < 8) ? src[512 + lane]
                                  : make_float4(0.f, 0.f, 0.f, 0.f);

    // ---- 2) B fragments (weights) under the load latency ----
    short8v Bhi[2][4], Blo[2][4];
    float biasv[2], wt0[2], wt1[2];
    #pragma unroll
    for (int t = 0; t < 2; ++t) {
        const int g = 16 * t + lr;
        const int gv = (g < 30) ? g : 0;
        #pragma unroll
        for (int q = 0; q < 4; ++q)
            load_split(Wf + (long)gv * II + 32 * q + 8 * lk, Bhi[t][q], Blo[t][q]);
        if (g >= 30) {                    // mask cols 30,31
            const short8v z = {0, 0, 0, 0, 0, 0, 0, 0};
            #pragma unroll
            for (int q = 0; q < 4; ++q) { Bhi[t][q] = z; Blo[t][q] = z; }
        }
        biasv[t] = bih[gv];
        const float2 wt = *(const float2*)(Wf + (long)gv * II + 128);
        wt0[t] = wt.x; wt1[t] = wt.y;
    }

    // ---- 3) stage tile to per-wave LDS (16 x 130 f32 = 8320 B) ----
    __shared__ __align__(16) float lds[4][16 * II];
    float4* __restrict__ L4 = (float4*)lds[wv];
    const float* __restrict__ Lf = lds[wv];
    L4[lane]       = pf0;  L4[64 + lane]  = pf1;
    L4[128 + lane] = pf2;  L4[192 + lane] = pf3;
    L4[256 + lane] = pf4;  L4[320 + lane] = pf5;
    L4[384 + lane] = pf6;  L4[448 + lane] = pf7;
    if (lane < 8) L4[512 + lane] = pft;

    // ---- 4) compute: K=128 via 4 k-blocks, 3-term bf16 emulation ----
    f32x4 a0 = (f32x4){biasv[0], biasv[0], biasv[0], biasv[0]};
    f32x4 a1 = (f32x4){biasv[1], biasv[1], biasv[1], biasv[1]};
    #pragma unroll
    for (int q = 0; q < 4; ++q) {
        short8v ahi, alo;
        load_split(Lf + lr * II + 32 * q + 8 * lk, ahi, alo);
        a0 = __builtin_amdgcn_mfma_f32_16x16x32_bf16(ahi, Bhi[0][q], a0, 0, 0, 0);
        a0 = __builtin_amdgcn_mfma_f32_16x16x32_bf16(ahi, Blo[0][q], a0, 0, 0, 0);
        a0 = __builtin_amdgcn_mfma_f32_16x16x32_bf16(alo, Bhi[0][q], a0, 0, 0, 0);
        a1 = __builtin_amdgcn_mfma_f32_16x16x32_bf16(ahi, Bhi[1][q], a1, 0, 0, 0);
        a1 = __builtin_amdgcn_mfma_f32_16x16x32_bf16(ahi, Blo[1][q], a1, 0, 0, 0);
        a1 = __builtin_amdgcn_mfma_f32_16x16x32_bf16(alo, Bhi[1][q], a1, 0, 0, 0);
    }

    // ---- 5) k-tail (cols 128,129) + store ----
    // C layout: col = lr, row-in-tile = 4*lk + r (verified rounds 6/7)
    const long gb = (long)gru * ROWS_PER_GRU;
    #pragma unroll
    for (int r = 0; r < 4; ++r) {
        const int rowin = 4 * lk + r;
        const float2 xt = *(const float2*)(Lf + rowin * II + 128);
        const long rr = row0 + rowin;
        float* __restrict__ xo = xi + (gb + rr) * 30;
        const float v0 = a0[r] + xt.x * wt0[0] + xt.y * wt1[0];
        xo[lr] = v0;                          // g = lr (0..15)
        if (lr < 14) {
            const float v1 = a1[r] + xt.x * wt0[1] + xt.y * wt1[1];
            xo[16 + lr] = v1;                 // g = 16+lr (16..29)
        }
    }
}

// ---------------- Phase 2: recurrent scan (shfl h-broadcast) ----------------
__global__ __launch_bounds__(256, 4)
void gru_scan(const float* __restrict__ xi,
              const float* __restrict__ ruWhh, const float* __restrict__ rubhh,
              const float* __restrict__ enWhh, const float* __restrict__ enbhh,
              const float* __restrict__ W1, const float* __restrict__ b1,
              const float* __restrict__ W2, const float* __restrict__ b2,
              float* __restrict__ out)
{
    const int tid  = threadIdx.x;
    const int wv   = tid >> 6;
    const int lane = tid & 63;
    const int c    = lane >> 5;        // chain slot in wave (0/1)
    const int k    = lane & 31;        // hidden index, 0..9 active
    const int kq   = (k < 10) ? k : 0;
    const int base = lane & 32;        // shfl base for this chain's half
    const int chain = (blockIdx.x * 4 + wv) * 2 + c;
    const int gru   = chain >> 11;
    const int b     = chain & (BB - 1);

    const float* __restrict__ Whh = gru ? enWhh : ruWhh;
    const float* __restrict__ bhh = gru ? enbhh : rubhh;

    float whhR[10], whhZ[10], whhN[10];
    #pragma unroll
    for (int j = 0; j < 10; ++j) {
        whhR[j] = Whh[kq * 10 + j];
        whhZ[j] = Whh[(10 + kq) * 10 + j];
        whhN[j] = Whh[(20 + kq) * 10 + j];
    }
    const float bR = bhh[kq], bZ = bhh[10 + kq], bN = bhh[20 + kq];

    float hown = 0.f;                  // lane k (k<10) owns h[k]

    const float* __restrict__ xrow =
        xi + ((long)gru * ROWS_PER_GRU + (long)b * TT) * 30;

    float xR0 = xrow[kq],      xZ0 = xrow[10 + kq],  xN0 = xrow[20 + kq];
    float xR1 = xrow[30 + kq], xZ1 = xrow[40 + kq],  xN1 = xrow[50 + kq];

    for (int t = 0; t < TT; ++t) {
        const float xR = xR0, xZ = xZ0, xN = xN0;
        xR0 = xR1; xZ0 = xZ1; xN0 = xN1;
        {
            const int tn = (t + 2 < TT) ? t + 2 : TT - 1;
            const float* __restrict__ xp = xrow + (long)tn * 30;
            xR1 = xp[kq]; xZ1 = xp[10 + kq]; xN1 = xp[20 + kq];
        }

        // broadcast h from owning lanes (addresses loop-invariant)
        const float h0 = __shfl(hown, base + 0);
        const float h1 = __shfl(hown, base + 1);
        const float h2 = __shfl(hown, base + 2);
        const float h3 = __shfl(hown, base + 3);
        const float h4 = __shfl(hown, base + 4);
        const float h5 = __shfl(hown, base + 5);
        const float h6 = __shfl(hown, base + 6);
        const float h7 = __shfl(hown, base + 7);
        const float h8 = __shfl(hown, base + 8);
        const float h9 = __shfl(hown, base + 9);

        float gr = bR, gz = bZ, gn = bN;
        gr = fmaf(whhR[0], h0, gr); gz = fmaf(whhZ[0], h0, gz); gn = fmaf(whhN[0], h0, gn);
        gr = fmaf(whhR[1], h1, gr); gz = fmaf(whhZ[1], h1, gz); gn = fmaf(whhN[1], h1, gn);
        gr = fmaf(whhR[2], h2, gr); gz = fmaf(whhZ[2], h2, gz); gn = fmaf(whhN[2], h2, gn);
        gr = fmaf(whhR[3], h3, gr); gz = fmaf(whhZ[3], h3, gz); gn = fmaf(whhN[3], h3, gn);
        gr = fmaf(whhR[4], h4, gr); gz = fmaf(whhZ[4], h4, gz); gn = fmaf(whhN[4], h4, gn);
        gr = fmaf(whhR[5], h5, gr); gz = fmaf(whhZ[5], h5, gz); gn = fmaf(whhN[5], h5, gn);
        gr = fmaf(whhR[6], h6, gr); gz = fmaf(whhZ[6], h6, gz); gn = fmaf(whhN[6], h6, gn);
        gr = fmaf(whhR[7], h7, gr); gz = fmaf(whhZ[7], h7, gz); gn = fmaf(whhN[7], h7, gn);
        gr = fmaf(whhR[8], h8, gr); gz = fmaf(whhZ[8], h8, gz); gn = fmaf(whhN[8], h8, gn);
        gr = fmaf(whhR[9], h9, gr); gz = fmaf(whhZ[9], h9, gz); gn = fmaf(whhN[9], h9, gn);

        const float r = sigmoidf_fast(xR + gr);
        const float z = sigmoidf_fast(xZ + gz);
        const float n = tanhf_fast(xN + r * gn);
        hown = fmaf(z, hown - n, n);   // (1-z)n + z*h
    }

    // ---- fused MLP tail ----
    float val = 0.f;
    if (k < 10) {
        float v = 0.f;
        #pragma unroll
        for (int d = 0; d < 20; ++d)
            v = fmaf(W2[d], W1[d * 20 + gru * 10 + k], v);
        val = v * hown;
        if (k == 0 && gru == 0) {
            float c0 = b2[0];
            #pragma unroll
            for (int d = 0; d < 20; ++d) c0 = fmaf(W2[d], b1[d], c0);
            val += c0;
        }
    }
    val += __shfl_xor(val, 8);
    val += __shfl_xor(val, 4);
    val += __shfl_xor(val, 2);
    val += __shfl_xor(val, 1);
    if (k == 0) atomicAdd(&out[b], val);
}

// ---------------- Fallback: monolithic kernel ----------------
__global__ __launch_bounds__(256, 4)
void gru_fused(const float* __restrict__ ru, const float* __restrict__ en,
               const float* __restrict__ ruWih, const float* __restrict__ ruWhh,
               const float* __restrict__ rubih, const float* __restrict__ rubhh,
               const float* __restrict__ enWih, const float* __restrict__ enWhh,
               const float* __restrict__ enbih, const float* __restrict__ enbhh,
               const float* __restrict__ W1, const float* __restrict__ b1,
               const float* __restrict__ W2, const float* __restrict__ b2,
               float* __restrict__ out)
{
    const int tid  = threadIdx.x;
    const int wv   = tid >> 6;
    const int lane = tid & 63;
    const int g    = lane & 31;
    const int h    = lane >> 5;
    const int wid  = blockIdx.x * 4 + wv;
    const int gru  = wid >> 11;
    const int b    = wid & (BB - 1);

    const float* __restrict__ x   = gru ? en    : ru;
    const float* __restrict__ Wih = gru ? enWih : ruWih;
    const float* __restrict__ Whh = gru ? enWhh : ruWhh;
    const float* __restrict__ bih = gru ? enbih : rubih;
    const float* __restrict__ bhh = gru ? enbhh : rubhh;

    __shared__ __align__(16) float lds[4][176];
    float* __restrict__ X    = lds[wv];
    float* __restrict__ PRE  = X + 132;
    float* __restrict__ Hbuf = X + 164;

    const int gq = (g < 30) ? g : 0;
    float wih[64];
    #pragma unroll
    for (int j = 0; j < 64; ++j) wih[j] = Wih[gq * II + h * 64 + j];
    const float w_e = Wih[gq * II + 128 + h];
    float whh[10];
    #pragma unroll
    for (int k = 0; k < 10; ++k) whh[k] = Whh[gq * 10 + k];
    const float bihg = bih[gq];
    const float bhhg = bhh[gq];

    if (lane < 12) Hbuf[lane] = 0.f;
    float hown = 0.f;

    const float* __restrict__ xrow = x + (size_t)b * (TT * II);
    float xa = xrow[lane];
    float xb = xrow[64 + lane];
    float xc = (lane < 2) ? xrow[128 + lane] : 0.f;

    for (int t = 0; t < TT; ++t) {
        X[lane] = xa;
        X[64 + lane] = xb;
        if (lane < 2) X[128 + lane] = xc;
        {
            const int tn = (t < TT - 1) ? t + 1 : t;
            const float* __restrict__ xn = xrow + (size_t)tn * II;
            xa = xn[lane];
            xb = xn[64 + lane];
            xc = (lane < 2) ? xn[128 + lane] : 0.f;
        }
        const float4 h03 = *(const float4*)(Hbuf);
        const float4 h47 = *(const float4*)(Hbuf + 4);
        const float2 h89 = *(const float2*)(Hbuf + 8);
        float gh0 = fmaf(whh[0], h03.x, bhhg);
        float gh1 = whh[1] * h03.y;
        gh0 = fmaf(whh[2], h03.z, gh0);
        gh1 = fmaf(whh[3], h03.w, gh1);
        gh0 = fmaf(whh[4], h47.x, gh0);
        gh1 = fmaf(whh[5], h47.y, gh1);
        gh0 = fmaf(whh[6], h47.z, gh0);
        gh1 = fmaf(whh[7], h47.w, gh1);
        gh0 = fmaf(whh[8], h89.x, gh0);
        gh1 = fmaf(whh[9], h89.y, gh1);
        const float gh = gh0 + gh1;

        float s0 = 0.f, s1 = 0.f, s2 = 0.f, s3 = 0.f;
        const float4* __restrict__ xb4 = (const float4*)(X + h * 64);
        #pragma unroll
        for (int c = 0; c < 16; ++c) {
            const float4 v = xb4[c];
            s0 = fmaf(wih[4 * c + 0], v.x, s0);
            s1 = fmaf(wih[4 * c + 1], v.y, s1);
            s2 = fmaf(wih[4 * c + 2], v.z, s2);
            s3 = fmaf(wih[4 * c + 3], v.w, s3);
        }
        float s = (s0 + s1) + (s2 + s3);
        s = fmaf(w_e, X[128 + h], s);
        s += __shfl_xor(s, 32);

        const float xiv = s + bihg;
        const float pre = xiv + gh;
        if (lane < 30) PRE[lane] = pre;
        const float rpre = PRE[(g - 20) & 31];
        const float zpre = PRE[(g - 10) & 31];
        const float r = sigmoidf_fast(rpre);
        const float z = sigmoidf_fast(zpre);
        const float n = tanhf_fast(xiv + r * gh);
        const float hnew = (1.f - z) * n + z * hown;
        hown = hnew;
        if (lane >= 20 && lane < 30) Hbuf[lane - 20] = hnew;
    }

    float val = 0.f;
    if (lane < 10) {
        const float hk = Hbuf[lane];
        float v = 0.f;
        #pragma unroll
        for (int d = 0; d < 20; ++d)
            v = fmaf(W2[d], W1[d * 20 + gru * 10 + lane], v);
        val = v * hk;
        if (lane == 0 && gru == 0) {
            float c0 = b2[0];
            #pragma unroll
            for (int d = 0; d < 20; ++d) c0 = fmaf(W2[d], b1[d], c0);
            val += c0;
        }
    }
    #pragma unroll
    for (int o = 32; o > 0; o >>= 1) val += __shfl_xor(val, o);
    if (lane == 0) atomicAdd(&out[b], val);
}

extern "C" void kernel_launch(void* const* d_in, const int* in_sizes, int n_in,
                              void* d_out, int out_size, void* d_ws, size_t ws_size,
                              hipStream_t stream) {
    (void)in_sizes; (void)n_in;
    const float* ru    = (const float*)d_in[0];
    const float* en    = (const float*)d_in[1];
    const float* ruWih = (const float*)d_in[2];
    const float* ruWhh = (const float*)d_in[3];
    const float* rubih = (const float*)d_in[4];
    const float* rubhh = (const float*)d_in[5];
    const float* enWih = (const float*)d_in[6];
    const float* enWhh = (const float*)d_in[7];
    const float* enbih = (const float*)d_in[8];
    const float* enbhh = (const float*)d_in[9];
    const float* W1    = (const float*)d_in[10];
    const float* b1    = (const float*)d_in[11];
    const float* W2    = (const float*)d_in[12];
    const float* b2    = (const float*)d_in[13];
    float* out = (float*)d_out;

    hipMemsetAsync(d_out, 0, (size_t)out_size * sizeof(float), stream);

    const size_t xi_bytes = (size_t)ROWS_TOTAL * 30 * sizeof(float);  // ~63 MB
    if (ws_size >= xi_bytes) {
        float* xi = (float*)d_ws;
        // 32768 one-tile waves = 8192 blocks
        xi_gemm<<<dim3(8192), dim3(256), 0, stream>>>(
            ru, en, ruWih, rubih, enWih, enbih, xi);
        gru_scan<<<dim3(512), dim3(256), 0, stream>>>(
            xi, ruWhh, rubhh, enWhh, enbhh, W1, b1, W2, b2, out);
    } else {
        gru_fused<<<dim3(1024), dim3(256), 0, stream>>>(
            ru, en, ruWih, ruWhh, rubih, rubhh,
            enWih, enWhh, enbih, enbhh, W1, b1, W2, b2, out);
    }
}